// Round 16
// baseline (825.926 us; speedup 1.0000x reference)
//
#include <hip/hip_runtime.h>
#include <math.h>

// Problem constants
#define HID 4096
#define NH  32
#define NKV 8
#define DH  128
#define SEQ 64
#define BS  16
#define MC  1024
#define QKV_N 6144                 // (NH + 2*NKV) * DH
#define NPAGES 64                  // MC / BS
#define KS2 8                      // GEMM K-split factor
#define GQ  4                      // NH / NKV
#define CSPLIT 8                   // attention: 128-token chunks
#define TPS 128                    // tokens per split
#define RT  32                     // tokens per round
#define NHQ (SEQ * NH)             // 2048 (s,qhead) pairs
#define SCALE 0.08838834764831845f

// Static device scratch (BSS) — immune to ws_size.
__device__ float g_qkv[SEQ * QKV_N];
__device__ float g_attn[SEQ * HID];
__device__ float g_part[KS2 * SEQ * QKV_N];     // 12.6 MB GEMM partials
__device__ float g_po[CSPLIT * NHQ * DH];       // attn o-partials
__device__ float g_pm[CSPLIT * NHQ];
__device__ float g_pl[CSPLIT * NHQ];

// ---------------------------------------------------------------------------
// LDS-free GEMM: P[ks][s][j] = sum_{k in split} X[s][k] * W[j][k].
// Block = 4 waves; wave owns 16 consecutive j (wave-uniform); lane = s.
// X slice (64 k) lives in VGPRs, reloaded per chunk (L2-hot, 1 MB total).
// W reads are wave-uniform -> scalar/broadcast path. Inner loop is pure FMA.
// ---------------------------------------------------------------------------
__global__ __launch_bounds__(256) void gemm_sreg(const float* __restrict__ X,
                                                 const float* __restrict__ W,
                                                 float* __restrict__ P,
                                                 int N, int K) {
    const int tid  = threadIdx.x;
    const int lane = tid & 63;
    const int w    = tid >> 6;
    const int jb   = blockIdx.x * 64 + w * 16;   // wave-uniform
    const int kspan = K / KS2;                   // 512
    const int k_lo  = blockIdx.y * kspan;

    float acc[16];
    #pragma unroll
    for (int jj = 0; jj < 16; ++jj) acc[jj] = 0.f;

    for (int kc = 0; kc < kspan; kc += 64) {
        const int k0 = k_lo + kc;
        // lane's X slice: row s=lane, 64 k in 16 float4 VGPRs
        float4 xf[16];
        const float4* xp = (const float4*)(X + (size_t)lane * K + k0);
        #pragma unroll
        for (int i = 0; i < 16; ++i) xf[i] = xp[i];

        #pragma unroll
        for (int jj = 0; jj < 16; ++jj) {
            const float4* wp = (const float4*)(W + (size_t)(jb + jj) * K + k0);
            float a0 = 0.f, a1 = 0.f;
            #pragma unroll
            for (int i = 0; i < 16; i += 2) {
                float4 w0 = wp[i];       // wave-uniform address
                float4 w1 = wp[i + 1];
                float4 x0 = xf[i];
                float4 x1 = xf[i + 1];
                a0 = fmaf(x0.x, w0.x, a0); a0 = fmaf(x0.y, w0.y, a0);
                a0 = fmaf(x0.z, w0.z, a0); a0 = fmaf(x0.w, w0.w, a0);
                a1 = fmaf(x1.x, w1.x, a1); a1 = fmaf(x1.y, w1.y, a1);
                a1 = fmaf(x1.z, w1.z, a1); a1 = fmaf(x1.w, w1.w, a1);
            }
            acc[jj] += a0 + a1;
        }
    }
    // write partials: lane s writes its 16 j's (L2 merges across jj)
    float* pb = P + (size_t)blockIdx.y * SEQ * N + (size_t)lane * N + jb;
    #pragma unroll
    for (int jj = 0; jj < 16; ++jj) pb[jj] = acc[jj];
}

// reduce over KS2 partials
__global__ __launch_bounds__(256) void reduce_ks(const float* __restrict__ P,
                                                 float* __restrict__ Y, int n4) {
    int t = blockIdx.x * 256 + threadIdx.x;
    if (t >= n4) return;
    const float4* p4 = (const float4*)P;
    float4 r = p4[t];
    #pragma unroll
    for (int i = 1; i < KS2; ++i) {
        float4 v = p4[t + (size_t)i * n4];
        r.x += v.x; r.y += v.y; r.z += v.z; r.w += v.w;
    }
    ((float4*)Y)[t] = r;
}

// ---------------------------------------------------------------------------
// Scalar RoPE (unchanged, verified). sincosf(x, &sin, &cos) — sin FIRST.
// ---------------------------------------------------------------------------
__global__ __launch_bounds__(256) void rope_scalar(float* __restrict__ qkv,
                                                   const int* __restrict__ ia,
                                                   const int* __restrict__ ib) {
    int t = blockIdx.x * 256 + threadIdx.x;
    if (t >= SEQ * (NH + NKV) * 64) return;
    int i = t & 63;
    int h = (t >> 6) % (NH + NKV);
    int s = t / ((NH + NKV) * 64);
    int pos = max(ia[s], ib[s]) - 1;
    float* base = qkv + (size_t)s * QKV_N + (size_t)h * DH;
    float ang = (float)pos / powf(10000.0f, (float)i * 2.0f / (float)DH);
    float sn, c;
    sincosf(ang, &sn, &c);
    float x1 = base[i];
    float x2 = base[i + 64];
    base[i]      = x1 * c - x2 * sn;
    base[i + 64] = x2 * c + x1 * sn;
}

// ---------------------------------------------------------------------------
// Flash-decode attention v7: in-register QK^T during staging (unchanged) +
// parity-split float4 PV (lane = (tg, dd): dims 4*dd..+3, tokens of parity tg).
// ---------------------------------------------------------------------------
__global__ __launch_bounds__(256) void attn_reg(const float* __restrict__ qkv,
                                                const float* __restrict__ k_cache,
                                                const float* __restrict__ v_cache,
                                                const int* __restrict__ ia,
                                                const int* __restrict__ ib,
                                                const int* __restrict__ block_tables,
                                                float* __restrict__ po,
                                                float* __restrict__ pm,
                                                float* __restrict__ pl) {
    __shared__ float Vlds[2][RT][136];    // 34.8 KB (pad 136: 2-way max)
    __shared__ float sc_lds[2][GQ][34];
    __shared__ int   btl[NPAGES];

    int b  = blockIdx.x;
    int t  = b & 7;
    int kv = (b >> 3) & 7;
    int s  = b >> 6;
    int tid = threadIdx.x;
    int lane = tid & 63;
    int g = tid >> 6;

    int L   = max(ia[s], ib[s]);
    int pos = L - 1;
    int c_lo = t * TPS;
    if (c_lo >= L) return;
    int c_hi = min(c_lo + TPS, L);
    int n = c_hi - c_lo;
    int nrounds = (n + RT - 1) >> 5;

    const int sr = tid >> 3;
    const int sq = tid & 7;

    if (tid < NPAGES) btl[tid] = block_tables[s * NPAGES + tid];
    __syncthreads();

    const float* knew = qkv + (size_t)s * QKV_N + (size_t)NH * DH + (size_t)kv * DH;
    const float* vnew = qkv + (size_t)s * QKV_N + (size_t)(NH + NKV) * DH + (size_t)kv * DH;

    float4 qf[GQ][4];
    #pragma unroll
    for (int gg = 0; gg < GQ; ++gg) {
        const float4* qr = (const float4*)(qkv + (size_t)s * QKV_N
                                           + (size_t)(kv * GQ + gg) * DH);
        #pragma unroll
        for (int j = 0; j < 4; ++j) {
            float4 v = qr[sq + 8 * j];
            v.x *= SCALE; v.y *= SCALE; v.z *= SCALE; v.w *= SCALE;
            qf[gg][j] = v;
        }
    }

    float4 ka0, ka1, ka2, ka3, va0, va1, va2, va3;
    bool vrow;

#define LOADR(BASE) do {                                                        \
    int cc = c_lo + (BASE) + sr;                                                \
    vrow = cc < c_hi;                                                           \
    int cs = vrow ? cc : pos;                                                   \
    const float* kp_ = (cs == pos) ? knew                                       \
        : k_cache + ((size_t)btl[cs >> 4] * BS + (cs & 15)) * (size_t)(NKV * DH)\
                  + (size_t)kv * DH;                                            \
    const float* vp_ = (cs == pos) ? vnew                                       \
        : v_cache + ((size_t)btl[cs >> 4] * BS + (cs & 15)) * (size_t)(NKV * DH)\
                  + (size_t)kv * DH;                                            \
    const float4* kp4_ = (const float4*)kp_;                                    \
    const float4* vp4_ = (const float4*)vp_;                                    \
    ka0 = kp4_[sq];      ka1 = kp4_[sq + 8];                                    \
    ka2 = kp4_[sq + 16]; ka3 = kp4_[sq + 24];                                   \
    va0 = vp4_[sq];      va1 = vp4_[sq + 8];                                    \
    va2 = vp4_[sq + 16]; va3 = vp4_[sq + 24];                                   \
} while (0)

#define DOT4(Q, K) ((Q).x*(K).x + (Q).y*(K).y + (Q).z*(K).z + (Q).w*(K).w)

#define STORER(BUF) do {                                                        \
    float pp0 = DOT4(qf[0][0],ka0)+DOT4(qf[0][1],ka1)                           \
              + DOT4(qf[0][2],ka2)+DOT4(qf[0][3],ka3);                          \
    float pp1 = DOT4(qf[1][0],ka0)+DOT4(qf[1][1],ka1)                           \
              + DOT4(qf[1][2],ka2)+DOT4(qf[1][3],ka3);                          \
    float pp2 = DOT4(qf[2][0],ka0)+DOT4(qf[2][1],ka1)                           \
              + DOT4(qf[2][2],ka2)+DOT4(qf[2][3],ka3);                          \
    float pp3 = DOT4(qf[3][0],ka0)+DOT4(qf[3][1],ka1)                           \
              + DOT4(qf[3][2],ka2)+DOT4(qf[3][3],ka3);                          \
    pp0 += __shfl_xor(pp0, 1, 64); pp0 += __shfl_xor(pp0, 2, 64);               \
    pp0 += __shfl_xor(pp0, 4, 64);                                              \
    pp1 += __shfl_xor(pp1, 1, 64); pp1 += __shfl_xor(pp1, 2, 64);               \
    pp1 += __shfl_xor(pp1, 4, 64);                                              \
    pp2 += __shfl_xor(pp2, 1, 64); pp2 += __shfl_xor(pp2, 2, 64);               \
    pp2 += __shfl_xor(pp2, 4, 64);                                              \
    pp3 += __shfl_xor(pp3, 1, 64); pp3 += __shfl_xor(pp3, 2, 64);               \
    pp3 += __shfl_xor(pp3, 4, 64);                                              \
    if (sq < 4) {                                                               \
        float ppsel = (sq == 0) ? pp0 : (sq == 1) ? pp1 : (sq == 2) ? pp2 : pp3;\
        sc_lds[BUF][sq][sr] = vrow ? ppsel : -1e30f;                            \
    }                                                                           \
    *(float4*)(&Vlds[BUF][sr][4 * sq])        = va0;                            \
    *(float4*)(&Vlds[BUF][sr][4 * (sq + 8)])  = va1;                            \
    *(float4*)(&Vlds[BUF][sr][4 * (sq + 16)]) = va2;                            \
    *(float4*)(&Vlds[BUF][sr][4 * (sq + 24)]) = va3;                            \
} while (0)

    LOADR(0);
    STORER(0);
    __syncthreads();

    float m = -1e30f, l = 0.f;
    float4 oacc = {0.f, 0.f, 0.f, 0.f};
    int cur = 0;
    const int tkn = lane & 31;
    const int tg  = lane >> 5;
    const int dd  = lane & 31;

    for (int r = 0; r < nrounds; ++r) {
        int base = r << 5;
        if (r + 1 < nrounds) LOADR(base + RT);

        float sco = sc_lds[cur][g][tkn];
        float rm = sco;
        #pragma unroll
        for (int off = 16; off; off >>= 1) rm = fmaxf(rm, __shfl_xor(rm, off, 64));
        float m_new = fmaxf(m, rm);
        float p = expf(sco - m_new);
        float ps = p;
        #pragma unroll
        for (int off = 16; off; off >>= 1) ps += __shfl_xor(ps, off, 64);
        float rescale = expf(m - m_new);
        l = l * rescale + ps;
        oacc.x *= rescale; oacc.y *= rescale;
        oacc.z *= rescale; oacc.w *= rescale;
        m = m_new;

        // PV: parity-split float4; p of invalid tokens is 0.
        int cnt = min(RT, n - base);
        for (int j = 0; j < cnt; j += 2) {
            float pj = __shfl(p, j + tg, 64);
            float4 v = *(const float4*)(&Vlds[cur][j + tg][4 * dd]);
            oacc.x = fmaf(pj, v.x, oacc.x);
            oacc.y = fmaf(pj, v.y, oacc.y);
            oacc.z = fmaf(pj, v.z, oacc.z);
            oacc.w = fmaf(pj, v.w, oacc.w);
        }

        if (r + 1 < nrounds) {
            STORER(cur ^ 1);
            __syncthreads();
            cur ^= 1;
        }
    }

    // merge parities and write
    oacc.x += __shfl_xor(oacc.x, 32, 64);
    oacc.y += __shfl_xor(oacc.y, 32, 64);
    oacc.z += __shfl_xor(oacc.z, 32, 64);
    oacc.w += __shfl_xor(oacc.w, 32, 64);

    int idx = t * NHQ + s * NH + kv * GQ + g;
    float* ob = po + (size_t)idx * DH;
    if (tg == 0) ((float4*)ob)[dd] = oacc;
    if (lane == 0) {
        pm[idx] = m;
        pl[idx] = l;
    }
#undef LOADR
#undef DOT4
#undef STORER
}

// ---------------------------------------------------------------------------
// Combine: block per (s,qh); active split count derived from L.
// ---------------------------------------------------------------------------
__global__ __launch_bounds__(128) void attn_combine(const float* __restrict__ po,
                                                    const float* __restrict__ pm,
                                                    const float* __restrict__ pl,
                                                    const int* __restrict__ ia,
                                                    const int* __restrict__ ib,
                                                    float* __restrict__ attn_out) {
    int sh = blockIdx.x;
    int s  = sh >> 5;
    int d  = threadIdx.x;
    int L  = max(ia[s], ib[s]);
    int nact = (L + TPS - 1) / TPS;
    float mv[CSPLIT];
    float M = -1e30f;
    for (int i = 0; i < nact; ++i) {
        mv[i] = pm[i * NHQ + sh];
        M = fmaxf(M, mv[i]);
    }
    float num = 0.f, denom = 0.f;
    for (int i = 0; i < nact; ++i) {
        float w = expf(mv[i] - M);
        denom += pl[i * NHQ + sh] * w;
        num   += po[(size_t)(i * NHQ + sh) * DH + d] * w;
    }
    attn_out[(size_t)sh * DH + d] = num / denom;
}

// ---------------------------------------------------------------------------
extern "C" void kernel_launch(void* const* d_in, const int* in_sizes, int n_in,
                              void* d_out, int out_size, void* d_ws, size_t ws_size,
                              hipStream_t stream) {
    const float *hidden = nullptr, *k_cache = nullptr, *v_cache = nullptr;
    const float *qkv_w = nullptr, *o_w = nullptr;
    const int *i64a = nullptr, *i64b = nullptr, *block_tables = nullptr;
    for (int i = 0; i < n_in; ++i) {
        switch (in_sizes[i]) {
            case SEQ * HID:          hidden = (const float*)d_in[i]; break;
            case 4096 * BS * NKV * DH:
                if (!k_cache) k_cache = (const float*)d_in[i];
                else          v_cache = (const float*)d_in[i];
                break;
            case QKV_N * HID:        qkv_w = (const float*)d_in[i]; break;
            case HID * HID:          o_w   = (const float*)d_in[i]; break;
            case SEQ * NPAGES:       block_tables = (const int*)d_in[i]; break;
            case SEQ:
                if (!i64a) i64a = (const int*)d_in[i];
                else       i64b = (const int*)d_in[i];
                break;
        }
    }
    float* out = (float*)d_out;

    static float* qkv_p  = nullptr;
    static float* attn_p = nullptr;
    static float* part_p = nullptr;
    static float* po_p   = nullptr;
    static float* pm_p   = nullptr;
    static float* pl_p   = nullptr;
    if (!qkv_p) {
        void* p;
        hipGetSymbolAddress(&p, HIP_SYMBOL(g_qkv));  qkv_p  = (float*)p;
        hipGetSymbolAddress(&p, HIP_SYMBOL(g_attn)); attn_p = (float*)p;
        hipGetSymbolAddress(&p, HIP_SYMBOL(g_part)); part_p = (float*)p;
        hipGetSymbolAddress(&p, HIP_SYMBOL(g_po));   po_p   = (float*)p;
        hipGetSymbolAddress(&p, HIP_SYMBOL(g_pm));   pm_p   = (float*)p;
        hipGetSymbolAddress(&p, HIP_SYMBOL(g_pl));   pl_p   = (float*)p;
    }

    // 1) QKV projection (LDS-free GEMM)
    gemm_sreg<<<dim3(QKV_N / 64, KS2), 256, 0, stream>>>(hidden, qkv_w, part_p,
                                                         QKV_N, HID);
    reduce_ks<<<(SEQ * QKV_N / 4 + 255) / 256, 256, 0, stream>>>(part_p, qkv_p,
                                                                 SEQ * QKV_N / 4);
    // 2) RoPE
    rope_scalar<<<(SEQ * (NH + NKV) * 64) / 256, 256, 0, stream>>>(qkv_p, i64a, i64b);
    // 3) Flash-decode attention
    attn_reg<<<SEQ * NKV * CSPLIT, 256, 0, stream>>>(qkv_p, k_cache, v_cache,
                                                     i64a, i64b, block_tables,
                                                     po_p, pm_p, pl_p);
    attn_combine<<<NHQ, 128, 0, stream>>>(po_p, pm_p, pl_p, i64a, i64b, attn_p);
    // 4) Output projection
    gemm_sreg<<<dim3(HID / 64, KS2), 256, 0, stream>>>(attn_p, o_w, part_p,
                                                       HID, HID);
    reduce_ks<<<(SEQ * HID / 4 + 255) / 256, 256, 0, stream>>>(part_p, out,
                                                               SEQ * HID / 4);
}

// Round 17
// 198.116 us; speedup vs baseline: 4.1689x; 4.1689x over previous
//
#include <hip/hip_runtime.h>
#include <math.h>

// Problem constants
#define HID 4096
#define NH  32
#define NKV 8
#define DH  128
#define SEQ 64
#define BS  16
#define MC  1024
#define QKV_N 6144                 // (NH + 2*NKV) * DH
#define NPAGES 64                  // MC / BS
#define KS  16                     // GEMM K-split factor
#define KC8 32                     // GEMM K-chunk
#define GQ  4                      // NH / NKV
#define CSPLIT 8                   // attention: 128-token chunks
#define TPS 128                    // tokens per split
#define RT  32                     // tokens per round
#define NHQ (SEQ * NH)             // 2048 (s,qhead) pairs
#define SCALE 0.08838834764831845f

// Static device scratch (BSS) — immune to ws_size.
__device__ float g_qkv[SEQ * QKV_N];
__device__ float g_attn[SEQ * HID];
__device__ float g_part[KS * SEQ * QKV_N];      // 25.2 MB GEMM partials
__device__ float g_po[CSPLIT * NHQ * DH];       // attn o-partials
__device__ float g_pm[CSPLIT * NHQ];
__device__ float g_pl[CSPLIT * NHQ];

// ---------------------------------------------------------------------------
// LDS-tiled GEMM, 8x8 register tile. Block: 64 s x 256 j; 256 threads.
// Thread (ty=tid>>5, tx=tid&31) owns rows {4ty..+3, 32+4ty..+3} and
// cols {4tx..+3, 128+4tx..+3}. Per kk: 4 ds_read_b128 -> 64 FMA.
// All inner-loop b128 reads are consecutive-lane (conflict-free).
// ---------------------------------------------------------------------------
__global__ __launch_bounds__(256) void gemm_tile8(const float* __restrict__ X,
                                                  const float* __restrict__ W,
                                                  float* __restrict__ P,
                                                  int N, int K) {
    __shared__ float Xs[KC8][68];    // 8.7 KB
    __shared__ float Ws[KC8][260];   // 33.3 KB
    const int tid = threadIdx.x;
    const int tx = tid & 31;
    const int ty = tid >> 5;
    const int jb = blockIdx.x * 256;
    const int kspan = K / KS;        // 256
    const int k_lo = blockIdx.y * kspan;

    float4 acc[8][2];
    #pragma unroll
    for (int i = 0; i < 8; ++i) {
        acc[i][0] = make_float4(0.f, 0.f, 0.f, 0.f);
        acc[i][1] = make_float4(0.f, 0.f, 0.f, 0.f);
    }

    for (int kc = 0; kc < kspan; kc += KC8) {
        const int k0 = k_lo + kc;
        // stage X: 64 s x 32 k (512 float4; 2/thread), transpose to Xs[k][s]
        #pragma unroll
        for (int r = 0; r < 2; ++r) {
            int idx = r * 256 + tid;
            int s  = idx >> 3;
            int k4 = idx & 7;
            float4 v = *(const float4*)(X + (size_t)s * K + k0 + k4 * 4);
            Xs[k4 * 4 + 0][s] = v.x;
            Xs[k4 * 4 + 1][s] = v.y;
            Xs[k4 * 4 + 2][s] = v.z;
            Xs[k4 * 4 + 3][s] = v.w;
        }
        // stage W: 256 j x 32 k (2048 float4; 8/thread), transpose to Ws[k][j]
        #pragma unroll
        for (int r = 0; r < 8; ++r) {
            int idx = r * 256 + tid;
            int j  = idx >> 3;
            int k4 = idx & 7;
            float4 v = *(const float4*)(W + (size_t)(jb + j) * K + k0 + k4 * 4);
            Ws[k4 * 4 + 0][j] = v.x;
            Ws[k4 * 4 + 1][j] = v.y;
            Ws[k4 * 4 + 2][j] = v.z;
            Ws[k4 * 4 + 3][j] = v.w;
        }
        __syncthreads();
        #pragma unroll
        for (int kk = 0; kk < KC8; ++kk) {
            float4 x0 = *(const float4*)(&Xs[kk][ty * 4]);
            float4 x1 = *(const float4*)(&Xs[kk][32 + ty * 4]);
            float4 w0 = *(const float4*)(&Ws[kk][tx * 4]);
            float4 w1 = *(const float4*)(&Ws[kk][128 + tx * 4]);
            float xs[8] = {x0.x, x0.y, x0.z, x0.w, x1.x, x1.y, x1.z, x1.w};
            #pragma unroll
            for (int i = 0; i < 8; ++i) {
                acc[i][0].x = fmaf(xs[i], w0.x, acc[i][0].x);
                acc[i][0].y = fmaf(xs[i], w0.y, acc[i][0].y);
                acc[i][0].z = fmaf(xs[i], w0.z, acc[i][0].z);
                acc[i][0].w = fmaf(xs[i], w0.w, acc[i][0].w);
                acc[i][1].x = fmaf(xs[i], w1.x, acc[i][1].x);
                acc[i][1].y = fmaf(xs[i], w1.y, acc[i][1].y);
                acc[i][1].z = fmaf(xs[i], w1.z, acc[i][1].z);
                acc[i][1].w = fmaf(xs[i], w1.w, acc[i][1].w);
            }
        }
        __syncthreads();
    }
    // write partials: 8 rows x 2 col-halves
    float* pb = P + (size_t)blockIdx.y * SEQ * N;
    #pragma unroll
    for (int i = 0; i < 8; ++i) {
        int s = (i < 4) ? (ty * 4 + i) : (32 + ty * 4 + (i - 4));
        *(float4*)(pb + (size_t)s * N + jb + tx * 4)       = acc[i][0];
        *(float4*)(pb + (size_t)s * N + jb + 128 + tx * 4) = acc[i][1];
    }
}

// reduce over KS partials
__global__ __launch_bounds__(256) void reduce_ks(const float* __restrict__ P,
                                                 float* __restrict__ Y, int n4) {
    int t = blockIdx.x * 256 + threadIdx.x;
    if (t >= n4) return;
    const float4* p4 = (const float4*)P;
    float4 r = p4[t];
    #pragma unroll
    for (int i = 1; i < KS; ++i) {
        float4 v = p4[t + (size_t)i * n4];
        r.x += v.x; r.y += v.y; r.z += v.z; r.w += v.w;
    }
    ((float4*)Y)[t] = r;
}

// ---------------------------------------------------------------------------
// Scalar RoPE (unchanged, verified). sincosf(x, &sin, &cos) — sin FIRST.
// ---------------------------------------------------------------------------
__global__ __launch_bounds__(256) void rope_scalar(float* __restrict__ qkv,
                                                   const int* __restrict__ ia,
                                                   const int* __restrict__ ib) {
    int t = blockIdx.x * 256 + threadIdx.x;
    if (t >= SEQ * (NH + NKV) * 64) return;
    int i = t & 63;
    int h = (t >> 6) % (NH + NKV);
    int s = t / ((NH + NKV) * 64);
    int pos = max(ia[s], ib[s]) - 1;
    float* base = qkv + (size_t)s * QKV_N + (size_t)h * DH;
    float ang = (float)pos / powf(10000.0f, (float)i * 2.0f / (float)DH);
    float sn, c;
    sincosf(ang, &sn, &c);
    float x1 = base[i];
    float x2 = base[i + 64];
    base[i]      = x1 * c - x2 * sn;
    base[i + 64] = x2 * c + x1 * sn;
}

// ---------------------------------------------------------------------------
// Flash-decode attention v7 (verified R16): in-register QK^T during staging +
// parity-split float4 PV.
// ---------------------------------------------------------------------------
__global__ __launch_bounds__(256) void attn_reg(const float* __restrict__ qkv,
                                                const float* __restrict__ k_cache,
                                                const float* __restrict__ v_cache,
                                                const int* __restrict__ ia,
                                                const int* __restrict__ ib,
                                                const int* __restrict__ block_tables,
                                                float* __restrict__ po,
                                                float* __restrict__ pm,
                                                float* __restrict__ pl) {
    __shared__ float Vlds[2][RT][136];
    __shared__ float sc_lds[2][GQ][34];
    __shared__ int   btl[NPAGES];

    int b  = blockIdx.x;
    int t  = b & 7;
    int kv = (b >> 3) & 7;
    int s  = b >> 6;
    int tid = threadIdx.x;
    int lane = tid & 63;
    int g = tid >> 6;

    int L   = max(ia[s], ib[s]);
    int pos = L - 1;
    int c_lo = t * TPS;
    if (c_lo >= L) return;
    int c_hi = min(c_lo + TPS, L);
    int n = c_hi - c_lo;
    int nrounds = (n + RT - 1) >> 5;

    const int sr = tid >> 3;
    const int sq = tid & 7;

    if (tid < NPAGES) btl[tid] = block_tables[s * NPAGES + tid];
    __syncthreads();

    const float* knew = qkv + (size_t)s * QKV_N + (size_t)NH * DH + (size_t)kv * DH;
    const float* vnew = qkv + (size_t)s * QKV_N + (size_t)(NH + NKV) * DH + (size_t)kv * DH;

    float4 qf[GQ][4];
    #pragma unroll
    for (int gg = 0; gg < GQ; ++gg) {
        const float4* qr = (const float4*)(qkv + (size_t)s * QKV_N
                                           + (size_t)(kv * GQ + gg) * DH);
        #pragma unroll
        for (int j = 0; j < 4; ++j) {
            float4 v = qr[sq + 8 * j];
            v.x *= SCALE; v.y *= SCALE; v.z *= SCALE; v.w *= SCALE;
            qf[gg][j] = v;
        }
    }

    float4 ka0, ka1, ka2, ka3, va0, va1, va2, va3;
    bool vrow;

#define LOADR(BASE) do {                                                        \
    int cc = c_lo + (BASE) + sr;                                                \
    vrow = cc < c_hi;                                                           \
    int cs = vrow ? cc : pos;                                                   \
    const float* kp_ = (cs == pos) ? knew                                       \
        : k_cache + ((size_t)btl[cs >> 4] * BS + (cs & 15)) * (size_t)(NKV * DH)\
                  + (size_t)kv * DH;                                            \
    const float* vp_ = (cs == pos) ? vnew                                       \
        : v_cache + ((size_t)btl[cs >> 4] * BS + (cs & 15)) * (size_t)(NKV * DH)\
                  + (size_t)kv * DH;                                            \
    const float4* kp4_ = (const float4*)kp_;                                    \
    const float4* vp4_ = (const float4*)vp_;                                    \
    ka0 = kp4_[sq];      ka1 = kp4_[sq + 8];                                    \
    ka2 = kp4_[sq + 16]; ka3 = kp4_[sq + 24];                                   \
    va0 = vp4_[sq];      va1 = vp4_[sq + 8];                                    \
    va2 = vp4_[sq + 16]; va3 = vp4_[sq + 24];                                   \
} while (0)

#define DOT4(Q, K) ((Q).x*(K).x + (Q).y*(K).y + (Q).z*(K).z + (Q).w*(K).w)

#define STORER(BUF) do {                                                        \
    float pp0 = DOT4(qf[0][0],ka0)+DOT4(qf[0][1],ka1)                           \
              + DOT4(qf[0][2],ka2)+DOT4(qf[0][3],ka3);                          \
    float pp1 = DOT4(qf[1][0],ka0)+DOT4(qf[1][1],ka1)                           \
              + DOT4(qf[1][2],ka2)+DOT4(qf[1][3],ka3);                          \
    float pp2 = DOT4(qf[2][0],ka0)+DOT4(qf[2][1],ka1)                           \
              + DOT4(qf[2][2],ka2)+DOT4(qf[2][3],ka3);                          \
    float pp3 = DOT4(qf[3][0],ka0)+DOT4(qf[3][1],ka1)                           \
              + DOT4(qf[3][2],ka2)+DOT4(qf[3][3],ka3);                          \
    pp0 += __shfl_xor(pp0, 1, 64); pp0 += __shfl_xor(pp0, 2, 64);               \
    pp0 += __shfl_xor(pp0, 4, 64);                                              \
    pp1 += __shfl_xor(pp1, 1, 64); pp1 += __shfl_xor(pp1, 2, 64);               \
    pp1 += __shfl_xor(pp1, 4, 64);                                              \
    pp2 += __shfl_xor(pp2, 1, 64); pp2 += __shfl_xor(pp2, 2, 64);               \
    pp2 += __shfl_xor(pp2, 4, 64);                                              \
    pp3 += __shfl_xor(pp3, 1, 64); pp3 += __shfl_xor(pp3, 2, 64);               \
    pp3 += __shfl_xor(pp3, 4, 64);                                              \
    if (sq < 4) {                                                               \
        float ppsel = (sq == 0) ? pp0 : (sq == 1) ? pp1 : (sq == 2) ? pp2 : pp3;\
        sc_lds[BUF][sq][sr] = vrow ? ppsel : -1e30f;                            \
    }                                                                           \
    *(float4*)(&Vlds[BUF][sr][4 * sq])        = va0;                            \
    *(float4*)(&Vlds[BUF][sr][4 * (sq + 8)])  = va1;                            \
    *(float4*)(&Vlds[BUF][sr][4 * (sq + 16)]) = va2;                            \
    *(float4*)(&Vlds[BUF][sr][4 * (sq + 24)]) = va3;                            \
} while (0)

    LOADR(0);
    STORER(0);
    __syncthreads();

    float m = -1e30f, l = 0.f;
    float4 oacc = {0.f, 0.f, 0.f, 0.f};
    int cur = 0;
    const int tkn = lane & 31;
    const int tg  = lane >> 5;
    const int dd  = lane & 31;

    for (int r = 0; r < nrounds; ++r) {
        int base = r << 5;
        if (r + 1 < nrounds) LOADR(base + RT);

        float sco = sc_lds[cur][g][tkn];
        float rm = sco;
        #pragma unroll
        for (int off = 16; off; off >>= 1) rm = fmaxf(rm, __shfl_xor(rm, off, 64));
        float m_new = fmaxf(m, rm);
        float p = expf(sco - m_new);
        float ps = p;
        #pragma unroll
        for (int off = 16; off; off >>= 1) ps += __shfl_xor(ps, off, 64);
        float rescale = expf(m - m_new);
        l = l * rescale + ps;
        oacc.x *= rescale; oacc.y *= rescale;
        oacc.z *= rescale; oacc.w *= rescale;
        m = m_new;

        int cnt = min(RT, n - base);
        for (int j = 0; j < cnt; j += 2) {
            float pj = __shfl(p, j + tg, 64);
            float4 v = *(const float4*)(&Vlds[cur][j + tg][4 * dd]);
            oacc.x = fmaf(pj, v.x, oacc.x);
            oacc.y = fmaf(pj, v.y, oacc.y);
            oacc.z = fmaf(pj, v.z, oacc.z);
            oacc.w = fmaf(pj, v.w, oacc.w);
        }

        if (r + 1 < nrounds) {
            STORER(cur ^ 1);
            __syncthreads();
            cur ^= 1;
        }
    }

    oacc.x += __shfl_xor(oacc.x, 32, 64);
    oacc.y += __shfl_xor(oacc.y, 32, 64);
    oacc.z += __shfl_xor(oacc.z, 32, 64);
    oacc.w += __shfl_xor(oacc.w, 32, 64);

    int idx = t * NHQ + s * NH + kv * GQ + g;
    float* ob = po + (size_t)idx * DH;
    if (tg == 0) ((float4*)ob)[dd] = oacc;
    if (lane == 0) {
        pm[idx] = m;
        pl[idx] = l;
    }
#undef LOADR
#undef DOT4
#undef STORER
}

// ---------------------------------------------------------------------------
// Combine: block per (s,qh); active split count derived from L.
// ---------------------------------------------------------------------------
__global__ __launch_bounds__(128) void attn_combine(const float* __restrict__ po,
                                                    const float* __restrict__ pm,
                                                    const float* __restrict__ pl,
                                                    const int* __restrict__ ia,
                                                    const int* __restrict__ ib,
                                                    float* __restrict__ attn_out) {
    int sh = blockIdx.x;
    int s  = sh >> 5;
    int d  = threadIdx.x;
    int L  = max(ia[s], ib[s]);
    int nact = (L + TPS - 1) / TPS;
    float mv[CSPLIT];
    float M = -1e30f;
    for (int i = 0; i < nact; ++i) {
        mv[i] = pm[i * NHQ + sh];
        M = fmaxf(M, mv[i]);
    }
    float num = 0.f, denom = 0.f;
    for (int i = 0; i < nact; ++i) {
        float w = expf(mv[i] - M);
        denom += pl[i * NHQ + sh] * w;
        num   += po[(size_t)(i * NHQ + sh) * DH + d] * w;
    }
    attn_out[(size_t)sh * DH + d] = num / denom;
}

// ---------------------------------------------------------------------------
extern "C" void kernel_launch(void* const* d_in, const int* in_sizes, int n_in,
                              void* d_out, int out_size, void* d_ws, size_t ws_size,
                              hipStream_t stream) {
    const float *hidden = nullptr, *k_cache = nullptr, *v_cache = nullptr;
    const float *qkv_w = nullptr, *o_w = nullptr;
    const int *i64a = nullptr, *i64b = nullptr, *block_tables = nullptr;
    for (int i = 0; i < n_in; ++i) {
        switch (in_sizes[i]) {
            case SEQ * HID:          hidden = (const float*)d_in[i]; break;
            case 4096 * BS * NKV * DH:
                if (!k_cache) k_cache = (const float*)d_in[i];
                else          v_cache = (const float*)d_in[i];
                break;
            case QKV_N * HID:        qkv_w = (const float*)d_in[i]; break;
            case HID * HID:          o_w   = (const float*)d_in[i]; break;
            case SEQ * NPAGES:       block_tables = (const int*)d_in[i]; break;
            case SEQ:
                if (!i64a) i64a = (const int*)d_in[i];
                else       i64b = (const int*)d_in[i];
                break;
        }
    }
    float* out = (float*)d_out;

    static float* qkv_p  = nullptr;
    static float* attn_p = nullptr;
    static float* part_p = nullptr;
    static float* po_p   = nullptr;
    static float* pm_p   = nullptr;
    static float* pl_p   = nullptr;
    if (!qkv_p) {
        void* p;
        hipGetSymbolAddress(&p, HIP_SYMBOL(g_qkv));  qkv_p  = (float*)p;
        hipGetSymbolAddress(&p, HIP_SYMBOL(g_attn)); attn_p = (float*)p;
        hipGetSymbolAddress(&p, HIP_SYMBOL(g_part)); part_p = (float*)p;
        hipGetSymbolAddress(&p, HIP_SYMBOL(g_po));   po_p   = (float*)p;
        hipGetSymbolAddress(&p, HIP_SYMBOL(g_pm));   pm_p   = (float*)p;
        hipGetSymbolAddress(&p, HIP_SYMBOL(g_pl));   pl_p   = (float*)p;
    }

    // 1) QKV projection (LDS-tiled 8x8)
    gemm_tile8<<<dim3(QKV_N / 256, KS), 256, 0, stream>>>(hidden, qkv_w, part_p,
                                                          QKV_N, HID);
    reduce_ks<<<(SEQ * QKV_N / 4 + 255) / 256, 256, 0, stream>>>(part_p, qkv_p,
                                                                 SEQ * QKV_N / 4);
    // 2) RoPE
    rope_scalar<<<(SEQ * (NH + NKV) * 64) / 256, 256, 0, stream>>>(qkv_p, i64a, i64b);
    // 3) Flash-decode attention
    attn_reg<<<SEQ * NKV * CSPLIT, 256, 0, stream>>>(qkv_p, k_cache, v_cache,
                                                     i64a, i64b, block_tables,
                                                     po_p, pm_p, pl_p);
    attn_combine<<<NHQ, 128, 0, stream>>>(po_p, pm_p, pl_p, i64a, i64b, attn_p);
    // 4) Output projection
    gemm_tile8<<<dim3(HID / 256, KS), 256, 0, stream>>>(attn_p, o_w, part_p,
                                                        HID, HID);
    reduce_ks<<<(SEQ * HID / 4 + 255) / 256, 256, 0, stream>>>(part_p, out,
                                                               SEQ * HID / 4);
}